// Round 1
// baseline (236.100 us; speedup 1.0000x reference)
//
#include <hip/hip_runtime.h>
#include <hip/hip_bf16.h>
#include <cmath>

typedef __attribute__((ext_vector_type(8))) short bf16x8;
typedef __attribute__((ext_vector_type(4))) float f32x4;
typedef __attribute__((ext_vector_type(4))) short short4v;

#define MFMA16(a,b,c) __builtin_amdgcn_mfma_f32_16x16x32_bf16((a),(b),(c),0,0,0)

__device__ __forceinline__ short f2bf(float x){
  unsigned u = __float_as_uint(x);
  u += 0x7fffu + ((u >> 16) & 1u);          // RNE
  return (short)(u >> 16);
}
__device__ __forceinline__ float bf2f(short h){
  return __uint_as_float(((unsigned)(unsigned short)h) << 16);
}
// 16B-chunk XOR swizzle within a [rows][64-short] tile; unit = 8 shorts
__device__ __forceinline__ int swz(int row, int c){ return (row << 3) | (c ^ (row & 7)); }

// ---------------- split kernels ----------------
__global__ void split_mat(const float* __restrict__ src, short* __restrict__ hi,
                          short* __restrict__ lo, int n){
  int i = blockIdx.x * 256 + threadIdx.x;
  if(i >= n) return;
  float x = src[i];
  short h = f2bf(x);
  hi[i] = h;
  if(lo) lo[i] = f2bf(x - bf2f(h));
}

// proj [8][512][64] -> BT [512][512], BT[h*64+c][d] = proj[h][d][c]
__global__ void split_proj(const float* __restrict__ src, short* __restrict__ hi,
                           short* __restrict__ lo){
  int i = blockIdx.x * 256 + threadIdx.x;   // i = n*512 + d
  int n = i >> 9, d = i & 511;
  int h = n >> 6, c = n & 63;
  float x = src[(h << 15) | (d << 6) | c];
  short hh = f2bf(x);
  hi[i] = hh;
  if(lo) lo[i] = f2bf(x - bf2f(hh));
}

// ---------------- GEMM: C[4096x512] = A[4096x512] * BT[512x512]^T ----------------
// NPROD: 1 = hi*hi only; 3 = hi*hi + hi*lo + lo*hi
// EPI: 0 = write bf16 hi/lo split (*scale); 1 = write bf16 transposed to vt[b,h,c,j]; 2 = fp32 + bias
template<int NPROD, int EPI>
__global__ __launch_bounds__(256) void gemm_k(
    const short* __restrict__ Ahi, const short* __restrict__ Alo,
    const short* __restrict__ Bhi, const short* __restrict__ Blo,
    short* __restrict__ O0, short* __restrict__ O1,
    float* __restrict__ Of, const float* __restrict__ bias, float scale)
{
  constexpr int K = 512;
  __shared__ __attribute__((aligned(16))) short sAhi[128*64];
  __shared__ __attribute__((aligned(16))) short sBhi[64*64];
  __shared__ __attribute__((aligned(16))) short sAlo[NPROD==3 ? 128*64 : 8];
  __shared__ __attribute__((aligned(16))) short sBlo[NPROD==3 ? 64*64 : 8];
  const int tid = threadIdx.x;
  const int m0 = blockIdx.x * 128, n0 = blockIdx.y * 64;
  const int w = tid >> 6, lane = tid & 63;
  const int wm = (w >> 1) * 64, wn = (w & 1) * 32;
  const int lr = lane & 15, lg = lane >> 4;

  f32x4 acc[4][2];
  for(int i=0;i<4;i++) for(int j=0;j<2;j++) acc[i][j] = f32x4{0.f,0.f,0.f,0.f};

  for(int kt = 0; kt < K; kt += 64){
    __syncthreads();
    for(int u = tid; u < 1024; u += 256){
      int row = u >> 3, c = u & 7;
      long ga = (long)(m0 + row) * K + kt + c*8;
      *(bf16x8*)(sAhi + swz(row,c)*8) = *(const bf16x8*)(Ahi + ga);
      if(NPROD == 3)
        *(bf16x8*)(sAlo + swz(row,c)*8) = *(const bf16x8*)(Alo + ga);
    }
    for(int u = tid; u < 512; u += 256){
      int row = u >> 3, c = u & 7;
      long ga = (long)(n0 + row) * K + kt + c*8;
      *(bf16x8*)(sBhi + swz(row,c)*8) = *(const bf16x8*)(Bhi + ga);
      if(NPROD == 3)
        *(bf16x8*)(sBlo + swz(row,c)*8) = *(const bf16x8*)(Blo + ga);
    }
    __syncthreads();
    #pragma unroll
    for(int ks = 0; ks < 2; ks++){
      bf16x8 ah[4], al[4], bh[2], bl[2];
      #pragma unroll
      for(int i=0;i<4;i++){
        int row = wm + i*16 + lr, c = ks*4 + lg;
        ah[i] = *(const bf16x8*)(sAhi + swz(row,c)*8);
        if(NPROD==3) al[i] = *(const bf16x8*)(sAlo + swz(row,c)*8);
      }
      #pragma unroll
      for(int j=0;j<2;j++){
        int row = wn + j*16 + lr, c = ks*4 + lg;
        bh[j] = *(const bf16x8*)(sBhi + swz(row,c)*8);
        if(NPROD==3) bl[j] = *(const bf16x8*)(sBlo + swz(row,c)*8);
      }
      #pragma unroll
      for(int i=0;i<4;i++)
        #pragma unroll
        for(int j=0;j<2;j++){
          acc[i][j] = MFMA16(ah[i], bh[j], acc[i][j]);
          if(NPROD==3){
            acc[i][j] = MFMA16(ah[i], bl[j], acc[i][j]);
            acc[i][j] = MFMA16(al[i], bh[j], acc[i][j]);
          }
        }
    }
  }
  // epilogue: C row = m0+wm+i*16+lg*4+r, col = n0+wn+j*16+lr
  #pragma unroll
  for(int i=0;i<4;i++){
    #pragma unroll
    for(int j=0;j<2;j++){
      int row = m0 + wm + i*16 + lg*4;
      int col = n0 + wn + j*16 + lr;
      if(EPI == 1){
        int bb = row >> 11;
        int hh = col >> 6, cc = col & 63;
        short4v pk;
        #pragma unroll
        for(int r=0;r<4;r++) pk[r] = f2bf(acc[i][j][r] * scale);
        long idx = ((long)((bb*8 + hh)*64 + cc) << 11) + (row & 2047);
        *(short4v*)(O0 + idx) = pk;
      } else {
        #pragma unroll
        for(int r=0;r<4;r++){
          float v = acc[i][j][r] * scale;
          long idx = (long)(row + r) * 512 + col;
          if(EPI == 0){
            short hh = f2bf(v);
            O0[idx] = hh;
            O1[idx] = f2bf(v - bf2f(hh));
          } else {
            Of[idx] = v + bias[col];
          }
        }
      }
    }
  }
}

// ---------------- fused attention ----------------
struct SpreadArgs { float sig2[8]; float nine[8]; float inv2[8]; };

__global__ __launch_bounds__(256) void attn_k(
    const short* __restrict__ qhHi, const short* __restrict__ qhLo,
    const short* __restrict__ khHi, const short* __restrict__ khLo,
    const short* __restrict__ vt,
    const float* __restrict__ coords,
    const unsigned char* __restrict__ kpm,
    short* __restrict__ Xhi, short* __restrict__ Xlo,
    SpreadArgs sa)
{
  __shared__ __attribute__((aligned(16))) short sKhi[64*64];
  __shared__ __attribute__((aligned(16))) short sKlo[64*64];
  __shared__ __attribute__((aligned(16))) short sV[64*64];
  __shared__ float sCj[64][4];
  __shared__ float sM[64];
  __shared__ __attribute__((aligned(16))) short sP[4][16][72]; // per-wave P tile, padded

  const int tid = threadIdx.x, w = tid >> 6, lane = tid & 63;
  const int lr = lane & 15, lg = lane >> 4;
  const int b = blockIdx.z, h = blockIdx.y, i0 = blockIdx.x * 64;
  const float sig2 = sa.sig2[h], nine = sa.nine[h], inv2 = sa.inv2[h];

  // Q fragments resident in registers (A-frag: row = lane&15, k = (lane>>4)*8)
  long qrow = (long)(b*2048 + i0 + w*16 + lr) * 512 + h*64;
  bf16x8 qhi[2], qlo[2];
  #pragma unroll
  for(int ks=0; ks<2; ks++){
    qhi[ks] = *(const bf16x8*)(qhHi + qrow + ks*32 + lg*8);
    qlo[ks] = *(const bf16x8*)(qhLo + qrow + ks*32 + lg*8);
  }
  // coords of this lane's 4 C-rows
  float ci[4][3];
  {
    int r0 = b*2048 + i0 + w*16 + lg*4;
    #pragma unroll
    for(int r=0;r<4;r++){
      ci[r][0] = coords[(long)(r0+r)*3 + 0];
      ci[r][1] = coords[(long)(r0+r)*3 + 1];
      ci[r][2] = coords[(long)(r0+r)*3 + 2];
    }
  }
  f32x4 oacc[4];
  for(int c=0;c<4;c++) oacc[c] = f32x4{0.f,0.f,0.f,0.f};
  float m[4], l[4];
  for(int r=0;r<4;r++){ m[r] = -1e30f; l[r] = 0.f; }

  for(int jt=0; jt<32; jt++){
    int j0 = jt*64;
    for(int u=tid; u<512; u+=256){
      int row = u>>3, cc = u&7;
      long gk = (long)(b*2048 + j0 + row)*512 + h*64 + cc*8;
      *(bf16x8*)(sKhi + swz(row,cc)*8) = *(const bf16x8*)(khHi + gk);
      *(bf16x8*)(sKlo + swz(row,cc)*8) = *(const bf16x8*)(khLo + gk);
      long gv = ((long)((b*8+h)*64 + row) << 11) + j0 + cc*8;
      *(bf16x8*)(sV + swz(row,cc)*8) = *(const bf16x8*)(vt + gv);
    }
    if(tid < 64){
      long cb = (long)(b*2048 + j0 + tid)*3;
      sCj[tid][0] = coords[cb]; sCj[tid][1] = coords[cb+1]; sCj[tid][2] = coords[cb+2];
      sM[tid] = kpm[b*2048 + j0 + tid] ? 1.f : 0.f;
    }
    __syncthreads();

    // S = (QK^T)/8 with 4-product hi/lo split (scale folded into qh)
    f32x4 s[4];
    #pragma unroll
    for(int jf=0;jf<4;jf++){
      f32x4 t = f32x4{0.f,0.f,0.f,0.f};
      #pragma unroll
      for(int ks=0;ks<2;ks++){
        int row = jf*16 + lr, c = ks*4 + lg;
        bf16x8 bh = *(const bf16x8*)(sKhi + swz(row,c)*8);
        bf16x8 bl = *(const bf16x8*)(sKlo + swz(row,c)*8);
        t = MFMA16(qhi[ks], bh, t);
        t = MFMA16(qhi[ks], bl, t);
        t = MFMA16(qlo[ks], bh, t);
        t = MFMA16(qlo[ks], bl, t);
      }
      s[jf] = t;
    }
    // RBF modulation + mask (squared domain, no sqrt)
    #pragma unroll
    for(int jf=0;jf<4;jf++){
      int j = jf*16 + lr;
      float cjx = sCj[j][0], cjy = sCj[j][1], cjz = sCj[j][2];
      float km = sM[j];
      #pragma unroll
      for(int r=0;r<4;r++){
        float dx = ci[r][0]-cjx, dy = ci[r][1]-cjy, dz = ci[r][2]-cjz;
        float d2 = dx*dx + dy*dy + dz*dz;
        float tt = fminf(fmaxf(d2, sig2), nine);
        float arg = tt * inv2;
        float sv = s[jf][r];
        sv *= __expf(sv < 0.f ? arg : -arg);
        if(d2 > nine || km != 0.f) sv = -1e30f;
        s[jf][r] = sv;
      }
    }
    // online softmax: row max over the 16-lane column group
    float pm[4];
    #pragma unroll
    for(int r=0;r<4;r++)
      pm[r] = fmaxf(fmaxf(s[0][r], s[1][r]), fmaxf(s[2][r], s[3][r]));
    #pragma unroll
    for(int d=1; d<16; d<<=1){
      #pragma unroll
      for(int r=0;r<4;r++) pm[r] = fmaxf(pm[r], __shfl_xor(pm[r], d));
    }
    float fr[4];
    #pragma unroll
    for(int r=0;r<4;r++){
      float mn = fmaxf(m[r], pm[r]);
      fr[r] = __expf(m[r] - mn);
      m[r] = mn;
    }
    float ps[4] = {0.f,0.f,0.f,0.f};
    #pragma unroll
    for(int jf=0;jf<4;jf++)
      #pragma unroll
      for(int r=0;r<4;r++){
        float p = __expf(s[jf][r] - m[r]);
        s[jf][r] = p;
        ps[r] += p;
      }
    #pragma unroll
    for(int d=1; d<16; d<<=1){
      #pragma unroll
      for(int r=0;r<4;r++) ps[r] += __shfl_xor(ps[r], d);
    }
    #pragma unroll
    for(int r=0;r<4;r++) l[r] = l[r]*fr[r] + ps[r];
    #pragma unroll
    for(int c=0;c<4;c++)
      #pragma unroll
      for(int r=0;r<4;r++) oacc[c][r] *= fr[r];
    // P -> per-wave LDS (C-layout write, A-layout read; same-wave so no barrier)
    #pragma unroll
    for(int jf=0;jf<4;jf++)
      #pragma unroll
      for(int r=0;r<4;r++)
        sP[w][lg*4 + r][jf*16 + lr] = f2bf(s[jf][r]);
    // PV
    #pragma unroll
    for(int js=0;js<2;js++){
      union { bf16x8 v8; short4v h4[2]; } pa;
      pa.h4[0] = *(const short4v*)(&sP[w][lr][js*32 + lg*8]);
      pa.h4[1] = *(const short4v*)(&sP[w][lr][js*32 + lg*8 + 4]);
      #pragma unroll
      for(int cf=0; cf<4; cf++){
        int vrow = cf*16 + lr, vc = js*4 + lg;
        bf16x8 vb = *(const bf16x8*)(sV + swz(vrow,vc)*8);
        oacc[cf] = MFMA16(pa.v8, vb, oacc[cf]);
      }
    }
    __syncthreads();
  }
  // epilogue: X[b*2048+i][h*64+c] as hi/lo split for the final GEMM
  #pragma unroll
  for(int cf=0; cf<4; cf++){
    #pragma unroll
    for(int r=0;r<4;r++){
      float v = oacc[cf][r] / l[r];
      long idx = (long)(b*2048 + i0 + w*16 + lg*4 + r)*512 + h*64 + cf*16 + lr;
      short hh = f2bf(v);
      Xhi[idx] = hh;
      Xlo[idx] = f2bf(v - bf2f(hh));
    }
  }
}

// ---------------- host ----------------
extern "C" void kernel_launch(void* const* d_in, const int* in_sizes, int n_in,
                              void* d_out, int out_size, void* d_ws, size_t ws_size,
                              hipStream_t stream){
  const float* q  = (const float*)d_in[0];
  const float* k  = (const float*)d_in[1];
  const float* v  = (const float*)d_in[2];
  const float* coords = (const float*)d_in[3];
  const unsigned char* kpm = (const unsigned char*)d_in[4];
  const float* qp = (const float*)d_in[5];
  const float* kp = (const float*)d_in[6];
  const float* vp = (const float*)d_in[7];
  const float* ow = (const float*)d_in[8];
  const float* ob = (const float*)d_in[9];
  float* out = (float*)d_out;

  char* ws = (char*)d_ws;
  const size_t S = (size_t)4096*512*2;      // one bf16 [4096][512] plane
  const size_t P = (size_t)512*512*2;       // one bf16 [512][512] plane
  if(ws_size < 12*S + 7*P) return;          // clean fail signal if ws too small
  short* q_hi = (short*)(ws + 0*S);
  short* q_lo = (short*)(ws + 1*S);
  short* k_hi = (short*)(ws + 2*S);
  short* k_lo = (short*)(ws + 3*S);
  short* v_hi = (short*)(ws + 4*S);
  short* qhHi = (short*)(ws + 5*S);
  short* qhLo = (short*)(ws + 6*S);
  short* khHi = (short*)(ws + 7*S);
  short* khLo = (short*)(ws + 8*S);
  short* vt   = (short*)(ws + 9*S);
  short* Xhi  = (short*)(ws + 10*S);
  short* Xlo  = (short*)(ws + 11*S);
  char* ws2 = ws + 12*S;
  short* BqHi = (short*)(ws2 + 0*P);
  short* BqLo = (short*)(ws2 + 1*P);
  short* BkHi = (short*)(ws2 + 2*P);
  short* BkLo = (short*)(ws2 + 3*P);
  short* BvHi = (short*)(ws2 + 4*P);
  short* WHi  = (short*)(ws2 + 5*P);
  short* WLo  = (short*)(ws2 + 6*P);

  SpreadArgs sa;
  for(int hh=0; hh<8; hh++){
    double t  = (1.0 - 0.02) * (double)hh / 7.0;
    double lg = pow(20.0, t);
    double sp = 3.7 + (lg - 1.0) / 19.0 * (20.0 - 3.7);
    float spf = (float)sp;
    sa.sig2[hh] = spf*spf;
    sa.nine[hh] = 9.f*spf*spf;
    sa.inv2[hh] = 1.f/(2.f*spf*spf);
  }

  const int NQ = 4096*512;
  split_mat<<<dim3(NQ/256), dim3(256), 0, stream>>>(q, q_hi, q_lo, NQ);
  split_mat<<<dim3(NQ/256), dim3(256), 0, stream>>>(k, k_hi, k_lo, NQ);
  split_mat<<<dim3(NQ/256), dim3(256), 0, stream>>>(v, v_hi, nullptr, NQ);
  split_mat<<<dim3(1024),   dim3(256), 0, stream>>>(ow, WHi, WLo, 512*512);
  split_proj<<<dim3(1024),  dim3(256), 0, stream>>>(qp, BqHi, BqLo);
  split_proj<<<dim3(1024),  dim3(256), 0, stream>>>(kp, BkHi, BkLo);
  split_proj<<<dim3(1024),  dim3(256), 0, stream>>>(vp, BvHi, nullptr);

  // qh scaled by 1/sqrt(dk)=0.125 (exact power of two, folded pre-split)
  gemm_k<3,0><<<dim3(32,8), dim3(256), 0, stream>>>(q_hi, q_lo, BqHi, BqLo,
        qhHi, qhLo, nullptr, nullptr, 0.125f);
  gemm_k<3,0><<<dim3(32,8), dim3(256), 0, stream>>>(k_hi, k_lo, BkHi, BkLo,
        khHi, khLo, nullptr, nullptr, 1.f);
  gemm_k<1,1><<<dim3(32,8), dim3(256), 0, stream>>>(v_hi, nullptr, BvHi, nullptr,
        vt, nullptr, nullptr, nullptr, 1.f);

  attn_k<<<dim3(32,8,2), dim3(256), 0, stream>>>(qhHi, qhLo, khHi, khLo, vt,
        coords, kpm, Xhi, Xlo, sa);

  gemm_k<3,2><<<dim3(32,8), dim3(256), 0, stream>>>(Xhi, Xlo, WHi, WLo,
        nullptr, nullptr, out, ob, 1.f);
}

// Round 5
// 205.515 us; speedup vs baseline: 1.1488x; 1.1488x over previous
//
#include <hip/hip_runtime.h>
#include <hip/hip_bf16.h>
#include <cmath>

typedef __attribute__((ext_vector_type(8))) short bf16x8;
typedef __attribute__((ext_vector_type(4))) float f32x4;
typedef __attribute__((ext_vector_type(4))) short short4v;

#define MFMA16(a,b,c) __builtin_amdgcn_mfma_f32_16x16x32_bf16((a),(b),(c),0,0,0)

__device__ __forceinline__ short f2bf(float x){
  unsigned u = __float_as_uint(x);
  u += 0x7fffu + ((u >> 16) & 1u);          // RNE
  return (short)(u >> 16);
}
__device__ __forceinline__ float bf2f(short h){
  return __uint_as_float(((unsigned)(unsigned short)h) << 16);
}
// 16B-chunk XOR swizzle within a [rows][64-short] tile; unit = 8 shorts
__device__ __forceinline__ int swz(int row, int c){ return (row << 3) | (c ^ (row & 7)); }

// ---------------- split kernels ----------------
__global__ void split_mat(const float* __restrict__ src, short* __restrict__ hi,
                          short* __restrict__ lo, int n){
  int i = blockIdx.x * 256 + threadIdx.x;
  if(i >= n) return;
  float x = src[i];
  short h = f2bf(x);
  hi[i] = h;
  if(lo) lo[i] = f2bf(x - bf2f(h));
}

// q,k,v -> hi/lo (v: hi only), one dispatch
__global__ void split3(const float* __restrict__ q, const float* __restrict__ k,
                       const float* __restrict__ v,
                       short* __restrict__ q_hi, short* __restrict__ q_lo,
                       short* __restrict__ k_hi, short* __restrict__ k_lo,
                       short* __restrict__ v_hi){
  int y = blockIdx.y;
  int i = blockIdx.x * 256 + threadIdx.x;
  if(y == 0){
    float x = q[i]; short h = f2bf(x);
    q_hi[i] = h; q_lo[i] = f2bf(x - bf2f(h));
  } else if(y == 1){
    float x = k[i]; short h = f2bf(x);
    k_hi[i] = h; k_lo[i] = f2bf(x - bf2f(h));
  } else {
    v_hi[i] = f2bf(v[i]);
  }
}

// proj [8][512][64] -> BT [512][512], BT[h*64+c][d] = proj[h][d][c]; 3 projections fused
__global__ void split_proj3(const float* __restrict__ qp, const float* __restrict__ kp,
                            const float* __restrict__ vp,
                            short* __restrict__ BqHi, short* __restrict__ BqLo,
                            short* __restrict__ BkHi, short* __restrict__ BkLo,
                            short* __restrict__ BvHi){
  int y = blockIdx.y;
  int i = blockIdx.x * 256 + threadIdx.x;   // i = n*512 + d
  int n = i >> 9, d = i & 511;
  int h = n >> 6, c = n & 63;
  long si = (long)((h << 15) | (d << 6) | c);
  if(y == 0){
    float x = qp[si]; short hh = f2bf(x);
    BqHi[i] = hh; BqLo[i] = f2bf(x - bf2f(hh));
  } else if(y == 1){
    float x = kp[si]; short hh = f2bf(x);
    BkHi[i] = hh; BkLo[i] = f2bf(x - bf2f(hh));
  } else {
    BvHi[i] = f2bf(vp[si]);
  }
}

// ---------------- fused projection GEMM (q,k,v in one dispatch via z) ----------------
// C[4096x512] = A[4096x512] * BT[512x512]^T
// z=0: q (3-prod, hi/lo out, scale 0.125); z=1: k (3-prod, hi/lo out); z=2: v (1-prod, vt out)
__global__ __launch_bounds__(256) void gemm_qkv(
    const short* __restrict__ q_hi, const short* __restrict__ q_lo,
    const short* __restrict__ k_hi, const short* __restrict__ k_lo,
    const short* __restrict__ v_hi,
    const short* __restrict__ BqHi, const short* __restrict__ BqLo,
    const short* __restrict__ BkHi, const short* __restrict__ BkLo,
    const short* __restrict__ BvHi,
    short* __restrict__ qhHi, short* __restrict__ qhLo,
    short* __restrict__ khHi, short* __restrict__ khLo,
    short* __restrict__ vt)
{
  constexpr int K = 512;
  __shared__ __attribute__((aligned(16))) short sAhi[128*64];
  __shared__ __attribute__((aligned(16))) short sBhi[64*64];
  __shared__ __attribute__((aligned(16))) short sAlo[128*64];
  __shared__ __attribute__((aligned(16))) short sBlo[64*64];
  const int tid = threadIdx.x;
  const int z = blockIdx.z;
  const bool three = (z < 2);
  const short* Ahi = z==0 ? q_hi : z==1 ? k_hi : v_hi;
  const short* Alo = z==0 ? q_lo : k_lo;
  const short* Bhi = z==0 ? BqHi : z==1 ? BkHi : BvHi;
  const short* Blo = z==0 ? BqLo : BkLo;
  const float scale = z==0 ? 0.125f : 1.f;
  const int m0 = blockIdx.x * 128, n0 = blockIdx.y * 64;
  const int w = tid >> 6, lane = tid & 63;
  const int wm = (w >> 1) * 64, wn = (w & 1) * 32;
  const int lr = lane & 15, lg = lane >> 4;

  f32x4 acc[4][2];
  for(int i=0;i<4;i++) for(int j=0;j<2;j++) acc[i][j] = f32x4{0.f,0.f,0.f,0.f};

  for(int kt = 0; kt < K; kt += 64){
    __syncthreads();
    for(int u = tid; u < 1024; u += 256){
      int row = u >> 3, c = u & 7;
      long ga = (long)(m0 + row) * K + kt + c*8;
      *(bf16x8*)(sAhi + swz(row,c)*8) = *(const bf16x8*)(Ahi + ga);
      if(three)
        *(bf16x8*)(sAlo + swz(row,c)*8) = *(const bf16x8*)(Alo + ga);
    }
    for(int u = tid; u < 512; u += 256){
      int row = u >> 3, c = u & 7;
      long ga = (long)(n0 + row) * K + kt + c*8;
      *(bf16x8*)(sBhi + swz(row,c)*8) = *(const bf16x8*)(Bhi + ga);
      if(three)
        *(bf16x8*)(sBlo + swz(row,c)*8) = *(const bf16x8*)(Blo + ga);
    }
    __syncthreads();
    #pragma unroll
    for(int ks = 0; ks < 2; ks++){
      bf16x8 ah[4], al[4], bh[2], bl[2];
      #pragma unroll
      for(int i=0;i<4;i++){
        int row = wm + i*16 + lr, c = ks*4 + lg;
        ah[i] = *(const bf16x8*)(sAhi + swz(row,c)*8);
        if(three) al[i] = *(const bf16x8*)(sAlo + swz(row,c)*8);
      }
      #pragma unroll
      for(int j=0;j<2;j++){
        int row = wn + j*16 + lr, c = ks*4 + lg;
        bh[j] = *(const bf16x8*)(sBhi + swz(row,c)*8);
        if(three) bl[j] = *(const bf16x8*)(sBlo + swz(row,c)*8);
      }
      #pragma unroll
      for(int i=0;i<4;i++)
        #pragma unroll
        for(int j=0;j<2;j++){
          acc[i][j] = MFMA16(ah[i], bh[j], acc[i][j]);
          if(three){
            acc[i][j] = MFMA16(ah[i], bl[j], acc[i][j]);
            acc[i][j] = MFMA16(al[i], bh[j], acc[i][j]);
          }
        }
    }
  }
  // epilogue
  #pragma unroll
  for(int i=0;i<4;i++){
    #pragma unroll
    for(int j=0;j<2;j++){
      int row = m0 + wm + i*16 + lg*4;
      int col = n0 + wn + j*16 + lr;
      if(z == 2){
        int bb = row >> 11;
        int hh = col >> 6, cc = col & 63;
        short4v pk;
        #pragma unroll
        for(int r=0;r<4;r++) pk[r] = f2bf(acc[i][j][r]);
        long idx = ((long)((bb*8 + hh)*64 + cc) << 11) + (row & 2047);
        *(short4v*)(vt + idx) = pk;
      } else {
        short* O0 = z==0 ? qhHi : khHi;
        short* O1 = z==0 ? qhLo : khLo;
        #pragma unroll
        for(int r=0;r<4;r++){
          float v = acc[i][j][r] * scale;
          long idx = (long)(row + r) * 512 + col;
          short hh = f2bf(v);
          O0[idx] = hh;
          O1[idx] = f2bf(v - bf2f(hh));
        }
      }
    }
  }
}

// ---------------- GEMM template (used for the final GEMM) ----------------
template<int NPROD, int EPI>
__global__ __launch_bounds__(256) void gemm_k(
    const short* __restrict__ Ahi, const short* __restrict__ Alo,
    const short* __restrict__ Bhi, const short* __restrict__ Blo,
    short* __restrict__ O0, short* __restrict__ O1,
    float* __restrict__ Of, const float* __restrict__ bias, float scale)
{
  constexpr int K = 512;
  __shared__ __attribute__((aligned(16))) short sAhi[128*64];
  __shared__ __attribute__((aligned(16))) short sBhi[64*64];
  __shared__ __attribute__((aligned(16))) short sAlo[NPROD==3 ? 128*64 : 8];
  __shared__ __attribute__((aligned(16))) short sBlo[NPROD==3 ? 64*64 : 8];
  const int tid = threadIdx.x;
  const int m0 = blockIdx.x * 128, n0 = blockIdx.y * 64;
  const int w = tid >> 6, lane = tid & 63;
  const int wm = (w >> 1) * 64, wn = (w & 1) * 32;
  const int lr = lane & 15, lg = lane >> 4;

  f32x4 acc[4][2];
  for(int i=0;i<4;i++) for(int j=0;j<2;j++) acc[i][j] = f32x4{0.f,0.f,0.f,0.f};

  for(int kt = 0; kt < K; kt += 64){
    __syncthreads();
    for(int u = tid; u < 1024; u += 256){
      int row = u >> 3, c = u & 7;
      long ga = (long)(m0 + row) * K + kt + c*8;
      *(bf16x8*)(sAhi + swz(row,c)*8) = *(const bf16x8*)(Ahi + ga);
      if(NPROD == 3)
        *(bf16x8*)(sAlo + swz(row,c)*8) = *(const bf16x8*)(Alo + ga);
    }
    for(int u = tid; u < 512; u += 256){
      int row = u >> 3, c = u & 7;
      long ga = (long)(n0 + row) * K + kt + c*8;
      *(bf16x8*)(sBhi + swz(row,c)*8) = *(const bf16x8*)(Bhi + ga);
      if(NPROD == 3)
        *(bf16x8*)(sBlo + swz(row,c)*8) = *(const bf16x8*)(Blo + ga);
    }
    __syncthreads();
    #pragma unroll
    for(int ks = 0; ks < 2; ks++){
      bf16x8 ah[4], al[4], bh[2], bl[2];
      #pragma unroll
      for(int i=0;i<4;i++){
        int row = wm + i*16 + lr, c = ks*4 + lg;
        ah[i] = *(const bf16x8*)(sAhi + swz(row,c)*8);
        if(NPROD==3) al[i] = *(const bf16x8*)(sAlo + swz(row,c)*8);
      }
      #pragma unroll
      for(int j=0;j<2;j++){
        int row = wn + j*16 + lr, c = ks*4 + lg;
        bh[j] = *(const bf16x8*)(sBhi + swz(row,c)*8);
        if(NPROD==3) bl[j] = *(const bf16x8*)(sBlo + swz(row,c)*8);
      }
      #pragma unroll
      for(int i=0;i<4;i++)
        #pragma unroll
        for(int j=0;j<2;j++){
          acc[i][j] = MFMA16(ah[i], bh[j], acc[i][j]);
          if(NPROD==3){
            acc[i][j] = MFMA16(ah[i], bl[j], acc[i][j]);
            acc[i][j] = MFMA16(al[i], bh[j], acc[i][j]);
          }
        }
    }
  }
  #pragma unroll
  for(int i=0;i<4;i++){
    #pragma unroll
    for(int j=0;j<2;j++){
      int row = m0 + wm + i*16 + lg*4;
      int col = n0 + wn + j*16 + lr;
      if(EPI == 1){
        int bb = row >> 11;
        int hh = col >> 6, cc = col & 63;
        short4v pk;
        #pragma unroll
        for(int r=0;r<4;r++) pk[r] = f2bf(acc[i][j][r] * scale);
        long idx = ((long)((bb*8 + hh)*64 + cc) << 11) + (row & 2047);
        *(short4v*)(O0 + idx) = pk;
      } else {
        #pragma unroll
        for(int r=0;r<4;r++){
          float v = acc[i][j][r] * scale;
          long idx = (long)(row + r) * 512 + col;
          if(EPI == 0){
            short hh = f2bf(v);
            O0[idx] = hh;
            O1[idx] = f2bf(v - bf2f(hh));
          } else {
            Of[idx] = v + bias[col];
          }
        }
      }
    }
  }
}

// ---------------- fused attention (r1 structure; 3-product QK) ----------------
struct SpreadArgs { float sig2[8]; float nine[8]; float inv2[8]; };

__global__ __launch_bounds__(256) void attn_k(
    const short* __restrict__ qhHi, const short* __restrict__ qhLo,
    const short* __restrict__ khHi, const short* __restrict__ khLo,
    const short* __restrict__ vt,
    const float* __restrict__ coords,
    const unsigned char* __restrict__ kpm,
    short* __restrict__ Xhi, short* __restrict__ Xlo,
    SpreadArgs sa)
{
  __shared__ __attribute__((aligned(16))) short sKhi[64*64];
  __shared__ __attribute__((aligned(16))) short sKlo[64*64];
  __shared__ __attribute__((aligned(16))) short sV[64*64];
  __shared__ float sCj[64][4];
  __shared__ float sM[64];
  __shared__ __attribute__((aligned(16))) short sP[4][16][72]; // per-wave P tile, padded

  const int tid = threadIdx.x, w = tid >> 6, lane = tid & 63;
  const int lr = lane & 15, lg = lane >> 4;
  const int b = blockIdx.z, h = blockIdx.y, i0 = blockIdx.x * 64;
  const float sig2 = sa.sig2[h], nine = sa.nine[h], inv2 = sa.inv2[h];

  // Q fragments resident in registers (A-frag: row = lane&15, k = (lane>>4)*8)
  long qrow = (long)(b*2048 + i0 + w*16 + lr) * 512 + h*64;
  bf16x8 qhi[2], qlo[2];
  #pragma unroll
  for(int ks=0; ks<2; ks++){
    qhi[ks] = *(const bf16x8*)(qhHi + qrow + ks*32 + lg*8);
    qlo[ks] = *(const bf16x8*)(qhLo + qrow + ks*32 + lg*8);
  }
  // coords of this lane's 4 C-rows
  float ci[4][3];
  {
    int r0 = b*2048 + i0 + w*16 + lg*4;
    #pragma unroll
    for(int r=0;r<4;r++){
      ci[r][0] = coords[(long)(r0+r)*3 + 0];
      ci[r][1] = coords[(long)(r0+r)*3 + 1];
      ci[r][2] = coords[(long)(r0+r)*3 + 2];
    }
  }
  f32x4 oacc[4];
  for(int c=0;c<4;c++) oacc[c] = f32x4{0.f,0.f,0.f,0.f};
  float m[4], l[4];
  for(int r=0;r<4;r++){ m[r] = -1e30f; l[r] = 0.f; }

  for(int jt=0; jt<32; jt++){
    int j0 = jt*64;
    for(int u=tid; u<512; u+=256){
      int row = u>>3, cc = u&7;
      long gk = (long)(b*2048 + j0 + row)*512 + h*64 + cc*8;
      *(bf16x8*)(sKhi + swz(row,cc)*8) = *(const bf16x8*)(khHi + gk);
      *(bf16x8*)(sKlo + swz(row,cc)*8) = *(const bf16x8*)(khLo + gk);
      long gv = ((long)((b*8+h)*64 + row) << 11) + j0 + cc*8;
      *(bf16x8*)(sV + swz(row,cc)*8) = *(const bf16x8*)(vt + gv);
    }
    if(tid < 64){
      long cb = (long)(b*2048 + j0 + tid)*3;
      sCj[tid][0] = coords[cb]; sCj[tid][1] = coords[cb+1]; sCj[tid][2] = coords[cb+2];
      sM[tid] = kpm[b*2048 + j0 + tid] ? 1.f : 0.f;
    }
    __syncthreads();

    // S = (QK^T)/8, 3-product hi/lo split (scale folded into qh; lo*lo dropped —
    // this exact product set validated at absmax 0.5 in round 2's first validation)
    f32x4 s[4];
    #pragma unroll
    for(int jf=0;jf<4;jf++){
      f32x4 t = f32x4{0.f,0.f,0.f,0.f};
      #pragma unroll
      for(int ks=0;ks<2;ks++){
        int row = jf*16 + lr, c = ks*4 + lg;
        bf16x8 bh = *(const bf16x8*)(sKhi + swz(row,c)*8);
        bf16x8 bl = *(const bf16x8*)(sKlo + swz(row,c)*8);
        t = MFMA16(qhi[ks], bh, t);
        t = MFMA16(qhi[ks], bl, t);
        t = MFMA16(qlo[ks], bh, t);
      }
      s[jf] = t;
    }
    // RBF modulation + mask (squared domain, no sqrt)
    #pragma unroll
    for(int jf=0;jf<4;jf++){
      int j = jf*16 + lr;
      float cjx = sCj[j][0], cjy = sCj[j][1], cjz = sCj[j][2];
      float km = sM[j];
      #pragma unroll
      for(int r=0;r<4;r++){
        float dx = ci[r][0]-cjx, dy = ci[r][1]-cjy, dz = ci[r][2]-cjz;
        float d2 = dx*dx + dy*dy + dz*dz;
        float tt = fminf(fmaxf(d2, sig2), nine);
        float arg = tt * inv2;
        float sv = s[jf][r];
        sv *= __expf(sv < 0.f ? arg : -arg);
        if(d2 > nine || km != 0.f) sv = -1e30f;
        s[jf][r] = sv;
      }
    }
    // online softmax: row max over the 16-lane column group (r1's unconditional form)
    float pm[4];
    #pragma unroll
    for(int r=0;r<4;r++)
      pm[r] = fmaxf(fmaxf(s[0][r], s[1][r]), fmaxf(s[2][r], s[3][r]));
    #pragma unroll
    for(int d=1; d<16; d<<=1){
      #pragma unroll
      for(int r=0;r<4;r++) pm[r] = fmaxf(pm[r], __shfl_xor(pm[r], d));
    }
    float fr[4];
    #pragma unroll
    for(int r=0;r<4;r++){
      float mn = fmaxf(m[r], pm[r]);
      fr[r] = __expf(m[r] - mn);
      m[r] = mn;
    }
    float ps[4] = {0.f,0.f,0.f,0.f};
    #pragma unroll
    for(int jf=0;jf<4;jf++)
      #pragma unroll
      for(int r=0;r<4;r++){
        float p = __expf(s[jf][r] - m[r]);
        s[jf][r] = p;
        ps[r] += p;
      }
    #pragma unroll
    for(int d=1; d<16; d<<=1){
      #pragma unroll
      for(int r=0;r<4;r++) ps[r] += __shfl_xor(ps[r], d);
    }
    #pragma unroll
    for(int r=0;r<4;r++) l[r] = l[r]*fr[r] + ps[r];
    #pragma unroll
    for(int c=0;c<4;c++)
      #pragma unroll
      for(int r=0;r<4;r++) oacc[c][r] *= fr[r];
    // P -> per-wave LDS (C-layout write, A-layout read; same-wave so no barrier)
    #pragma unroll
    for(int jf=0;jf<4;jf++)
      #pragma unroll
      for(int r=0;r<4;r++)
        sP[w][lg*4 + r][jf*16 + lr] = f2bf(s[jf][r]);
    // PV
    #pragma unroll
    for(int js=0;js<2;js++){
      union { bf16x8 v8; short4v h4[2]; } pa;
      pa.h4[0] = *(const short4v*)(&sP[w][lr][js*32 + lg*8]);
      pa.h4[1] = *(const short4v*)(&sP[w][lr][js*32 + lg*8 + 4]);
      #pragma unroll
      for(int cf=0; cf<4; cf++){
        int vrow = cf*16 + lr, vc = js*4 + lg;
        bf16x8 vb = *(const bf16x8*)(sV + swz(vrow,vc)*8);
        oacc[cf] = MFMA16(pa.v8, vb, oacc[cf]);
      }
    }
    __syncthreads();
  }
  // epilogue: X[b*2048+i][h*64+c] as hi/lo split for the final GEMM
  #pragma unroll
  for(int cf=0; cf<4; cf++){
    #pragma unroll
    for(int r=0;r<4;r++){
      float v = oacc[cf][r] / l[r];
      long idx = (long)(b*2048 + i0 + w*16 + lg*4 + r)*512 + h*64 + cf*16 + lr;
      short hh = f2bf(v);
      Xhi[idx] = hh;
      Xlo[idx] = f2bf(v - bf2f(hh));
    }
  }
}

// ---------------- host ----------------
extern "C" void kernel_launch(void* const* d_in, const int* in_sizes, int n_in,
                              void* d_out, int out_size, void* d_ws, size_t ws_size,
                              hipStream_t stream){
  const float* q  = (const float*)d_in[0];
  const float* k  = (const float*)d_in[1];
  const float* v  = (const float*)d_in[2];
  const float* coords = (const float*)d_in[3];
  const unsigned char* kpm = (const unsigned char*)d_in[4];
  const float* qp = (const float*)d_in[5];
  const float* kp = (const float*)d_in[6];
  const float* vp = (const float*)d_in[7];
  const float* ow = (const float*)d_in[8];
  const float* ob = (const float*)d_in[9];
  float* out = (float*)d_out;

  char* ws = (char*)d_ws;
  const size_t S = (size_t)4096*512*2;      // one bf16 [4096][512] plane
  const size_t P = (size_t)512*512*2;       // one bf16 [512][512] plane
  if(ws_size < 12*S + 7*P) return;
  short* q_hi = (short*)(ws + 0*S);
  short* q_lo = (short*)(ws + 1*S);
  short* k_hi = (short*)(ws + 2*S);
  short* k_lo = (short*)(ws + 3*S);
  short* v_hi = (short*)(ws + 4*S);
  short* qhHi = (short*)(ws + 5*S);
  short* qhLo = (short*)(ws + 6*S);
  short* khHi = (short*)(ws + 7*S);
  short* khLo = (short*)(ws + 8*S);
  short* vt   = (short*)(ws + 9*S);
  short* Xhi  = (short*)(ws + 10*S);
  short* Xlo  = (short*)(ws + 11*S);
  char* ws2 = ws + 12*S;
  short* BqHi = (short*)(ws2 + 0*P);
  short* BqLo = (short*)(ws2 + 1*P);
  short* BkHi = (short*)(ws2 + 2*P);
  short* BkLo = (short*)(ws2 + 3*P);
  short* BvHi = (short*)(ws2 + 4*P);
  short* WHi  = (short*)(ws2 + 5*P);
  short* WLo  = (short*)(ws2 + 6*P);

  SpreadArgs sa;
  for(int hh=0; hh<8; hh++){
    double t  = (1.0 - 0.02) * (double)hh / 7.0;
    double lg = pow(20.0, t);
    double sp = 3.7 + (lg - 1.0) / 19.0 * (20.0 - 3.7);
    float spf = (float)sp;
    sa.sig2[hh] = spf*spf;
    sa.nine[hh] = 9.f*spf*spf;
    sa.inv2[hh] = 1.f/(2.f*spf*spf);
  }

  const int NQ = 4096*512;
  split3<<<dim3(NQ/256, 3), dim3(256), 0, stream>>>(q, k, v, q_hi, q_lo, k_hi, k_lo, v_hi);
  split_mat<<<dim3(1024), dim3(256), 0, stream>>>(ow, WHi, WLo, 512*512);
  split_proj3<<<dim3(1024, 3), dim3(256), 0, stream>>>(qp, kp, vp, BqHi, BqLo, BkHi, BkLo, BvHi);

  gemm_qkv<<<dim3(32, 8, 3), dim3(256), 0, stream>>>(
      q_hi, q_lo, k_hi, k_lo, v_hi,
      BqHi, BqLo, BkHi, BkLo, BvHi,
      qhHi, qhLo, khHi, khLo, vt);

  attn_k<<<dim3(32, 8, 2), dim3(256), 0, stream>>>(qhHi, qhLo, khHi, khLo, vt,
        coords, kpm, Xhi, Xlo, sa);

  gemm_k<3,2><<<dim3(32, 8), dim3(256), 0, stream>>>(Xhi, Xlo, WHi, WLo,
        nullptr, nullptr, out, ob, 1.f);
}

// Round 7
// 197.460 us; speedup vs baseline: 1.1957x; 1.0408x over previous
//
#include <hip/hip_runtime.h>
#include <hip/hip_bf16.h>
#include <cmath>

typedef __attribute__((ext_vector_type(8))) short bf16x8;
typedef __attribute__((ext_vector_type(4))) float f32x4;
typedef __attribute__((ext_vector_type(4))) short short4v;

#define MFMA16(a,b,c) __builtin_amdgcn_mfma_f32_16x16x32_bf16((a),(b),(c),0,0,0)

__device__ __forceinline__ short f2bf(float x){
  unsigned u = __float_as_uint(x);
  u += 0x7fffu + ((u >> 16) & 1u);          // RNE
  return (short)(u >> 16);
}
__device__ __forceinline__ float bf2f(short h){
  return __uint_as_float(((unsigned)(unsigned short)h) << 16);
}
// 16B-chunk XOR swizzle within a [rows][64-short] tile; unit = 8 shorts
__device__ __forceinline__ int swz(int row, int c){ return (row << 3) | (c ^ (row & 7)); }

// ---------------- split kernels ----------------
__global__ void split_mat(const float* __restrict__ src, short* __restrict__ hi,
                          short* __restrict__ lo, int n){
  int i = blockIdx.x * 256 + threadIdx.x;
  if(i >= n) return;
  float x = src[i];
  short h = f2bf(x);
  hi[i] = h;
  if(lo) lo[i] = f2bf(x - bf2f(h));
}

// q,k,v -> hi/lo (v: hi only), one dispatch
__global__ void split3(const float* __restrict__ q, const float* __restrict__ k,
                       const float* __restrict__ v,
                       short* __restrict__ q_hi, short* __restrict__ q_lo,
                       short* __restrict__ k_hi, short* __restrict__ k_lo,
                       short* __restrict__ v_hi){
  int y = blockIdx.y;
  int i = blockIdx.x * 256 + threadIdx.x;
  if(y == 0){
    float x = q[i]; short h = f2bf(x);
    q_hi[i] = h; q_lo[i] = f2bf(x - bf2f(h));
  } else if(y == 1){
    float x = k[i]; short h = f2bf(x);
    k_hi[i] = h; k_lo[i] = f2bf(x - bf2f(h));
  } else {
    v_hi[i] = f2bf(v[i]);
  }
}

// proj [8][512][64] -> BT [512][512], BT[h*64+c][d] = proj[h][d][c]; 3 projections fused
__global__ void split_proj3(const float* __restrict__ qp, const float* __restrict__ kp,
                            const float* __restrict__ vp,
                            short* __restrict__ BqHi, short* __restrict__ BqLo,
                            short* __restrict__ BkHi, short* __restrict__ BkLo,
                            short* __restrict__ BvHi){
  int y = blockIdx.y;
  int i = blockIdx.x * 256 + threadIdx.x;   // i = n*512 + d
  int n = i >> 9, d = i & 511;
  int h = n >> 6, c = n & 63;
  long si = (long)((h << 15) | (d << 6) | c);
  if(y == 0){
    float x = qp[si]; short hh = f2bf(x);
    BqHi[i] = hh; BqLo[i] = f2bf(x - bf2f(hh));
  } else if(y == 1){
    float x = kp[si]; short hh = f2bf(x);
    BkHi[i] = hh; BkLo[i] = f2bf(x - bf2f(hh));
  } else {
    BvHi[i] = f2bf(vp[si]);
  }
}

// ---------------- fused projection GEMM (q,k,v in one dispatch via z) ----------------
// C[4096x512] = A[4096x512] * BT[512x512]^T
// z=0: q (3-prod, hi/lo out, scale 0.125); z=1: k (3-prod, hi/lo out); z=2: v (1-prod, vt out)
__global__ __launch_bounds__(256) void gemm_qkv(
    const short* __restrict__ q_hi, const short* __restrict__ q_lo,
    const short* __restrict__ k_hi, const short* __restrict__ k_lo,
    const short* __restrict__ v_hi,
    const short* __restrict__ BqHi, const short* __restrict__ BqLo,
    const short* __restrict__ BkHi, const short* __restrict__ BkLo,
    const short* __restrict__ BvHi,
    short* __restrict__ qhHi, short* __restrict__ qhLo,
    short* __restrict__ khHi, short* __restrict__ khLo,
    short* __restrict__ vt)
{
  constexpr int K = 512;
  __shared__ __attribute__((aligned(16))) short sAhi[128*64];
  __shared__ __attribute__((aligned(16))) short sBhi[64*64];
  __shared__ __attribute__((aligned(16))) short sAlo[128*64];
  __shared__ __attribute__((aligned(16))) short sBlo[64*64];
  const int tid = threadIdx.x;
  const int z = blockIdx.z;
  const bool three = (z < 2);
  const short* Ahi = z==0 ? q_hi : z==1 ? k_hi : v_hi;
  const short* Alo = z==0 ? q_lo : k_lo;
  const short* Bhi = z==0 ? BqHi : z==1 ? BkHi : BvHi;
  const short* Blo = z==0 ? BqLo : BkLo;
  const float scale = z==0 ? 0.125f : 1.f;
  const int m0 = blockIdx.x * 128, n0 = blockIdx.y * 64;
  const int w = tid >> 6, lane = tid & 63;
  const int wm = (w >> 1) * 64, wn = (w & 1) * 32;
  const int lr = lane & 15, lg = lane >> 4;

  f32x4 acc[4][2];
  for(int i=0;i<4;i++) for(int j=0;j<2;j++) acc[i][j] = f32x4{0.f,0.f,0.f,0.f};

  for(int kt = 0; kt < K; kt += 64){
    __syncthreads();
    for(int u = tid; u < 1024; u += 256){
      int row = u >> 3, c = u & 7;
      long ga = (long)(m0 + row) * K + kt + c*8;
      *(bf16x8*)(sAhi + swz(row,c)*8) = *(const bf16x8*)(Ahi + ga);
      if(three)
        *(bf16x8*)(sAlo + swz(row,c)*8) = *(const bf16x8*)(Alo + ga);
    }
    for(int u = tid; u < 512; u += 256){
      int row = u >> 3, c = u & 7;
      long ga = (long)(n0 + row) * K + kt + c*8;
      *(bf16x8*)(sBhi + swz(row,c)*8) = *(const bf16x8*)(Bhi + ga);
      if(three)
        *(bf16x8*)(sBlo + swz(row,c)*8) = *(const bf16x8*)(Blo + ga);
    }
    __syncthreads();
    #pragma unroll
    for(int ks = 0; ks < 2; ks++){
      bf16x8 ah[4], al[4], bh[2], bl[2];
      #pragma unroll
      for(int i=0;i<4;i++){
        int row = wm + i*16 + lr, c = ks*4 + lg;
        ah[i] = *(const bf16x8*)(sAhi + swz(row,c)*8);
        if(three) al[i] = *(const bf16x8*)(sAlo + swz(row,c)*8);
      }
      #pragma unroll
      for(int j=0;j<2;j++){
        int row = wn + j*16 + lr, c = ks*4 + lg;
        bh[j] = *(const bf16x8*)(sBhi + swz(row,c)*8);
        if(three) bl[j] = *(const bf16x8*)(sBlo + swz(row,c)*8);
      }
      #pragma unroll
      for(int i=0;i<4;i++)
        #pragma unroll
        for(int j=0;j<2;j++){
          acc[i][j] = MFMA16(ah[i], bh[j], acc[i][j]);
          if(three){
            acc[i][j] = MFMA16(ah[i], bl[j], acc[i][j]);
            acc[i][j] = MFMA16(al[i], bh[j], acc[i][j]);
          }
        }
    }
  }
  // epilogue
  #pragma unroll
  for(int i=0;i<4;i++){
    #pragma unroll
    for(int j=0;j<2;j++){
      int row = m0 + wm + i*16 + lg*4;
      int col = n0 + wn + j*16 + lr;
      if(z == 2){
        int bb = row >> 11;
        int hh = col >> 6, cc = col & 63;
        short4v pk;
        #pragma unroll
        for(int r=0;r<4;r++) pk[r] = f2bf(acc[i][j][r]);
        long idx = ((long)((bb*8 + hh)*64 + cc) << 11) + (row & 2047);
        *(short4v*)(vt + idx) = pk;
      } else {
        short* O0 = z==0 ? qhHi : khHi;
        short* O1 = z==0 ? qhLo : khLo;
        #pragma unroll
        for(int r=0;r<4;r++){
          float v = acc[i][j][r] * scale;
          long idx = (long)(row + r) * 512 + col;
          short hh = f2bf(v);
          O0[idx] = hh;
          O1[idx] = f2bf(v - bf2f(hh));
        }
      }
    }
  }
}

// ---------------- GEMM template (used for the final GEMM) ----------------
template<int NPROD, int EPI>
__global__ __launch_bounds__(256) void gemm_k(
    const short* __restrict__ Ahi, const short* __restrict__ Alo,
    const short* __restrict__ Bhi, const short* __restrict__ Blo,
    short* __restrict__ O0, short* __restrict__ O1,
    float* __restrict__ Of, const float* __restrict__ bias, float scale)
{
  constexpr int K = 512;
  __shared__ __attribute__((aligned(16))) short sAhi[128*64];
  __shared__ __attribute__((aligned(16))) short sBhi[64*64];
  __shared__ __attribute__((aligned(16))) short sAlo[NPROD==3 ? 128*64 : 8];
  __shared__ __attribute__((aligned(16))) short sBlo[NPROD==3 ? 64*64 : 8];
  const int tid = threadIdx.x;
  const int m0 = blockIdx.x * 128, n0 = blockIdx.y * 64;
  const int w = tid >> 6, lane = tid & 63;
  const int wm = (w >> 1) * 64, wn = (w & 1) * 32;
  const int lr = lane & 15, lg = lane >> 4;

  f32x4 acc[4][2];
  for(int i=0;i<4;i++) for(int j=0;j<2;j++) acc[i][j] = f32x4{0.f,0.f,0.f,0.f};

  for(int kt = 0; kt < K; kt += 64){
    __syncthreads();
    for(int u = tid; u < 1024; u += 256){
      int row = u >> 3, c = u & 7;
      long ga = (long)(m0 + row) * K + kt + c*8;
      *(bf16x8*)(sAhi + swz(row,c)*8) = *(const bf16x8*)(Ahi + ga);
      if(NPROD == 3)
        *(bf16x8*)(sAlo + swz(row,c)*8) = *(const bf16x8*)(Alo + ga);
    }
    for(int u = tid; u < 512; u += 256){
      int row = u >> 3, c = u & 7;
      long ga = (long)(n0 + row) * K + kt + c*8;
      *(bf16x8*)(sBhi + swz(row,c)*8) = *(const bf16x8*)(Bhi + ga);
      if(NPROD == 3)
        *(bf16x8*)(sBlo + swz(row,c)*8) = *(const bf16x8*)(Blo + ga);
    }
    __syncthreads();
    #pragma unroll
    for(int ks = 0; ks < 2; ks++){
      bf16x8 ah[4], al[4], bh[2], bl[2];
      #pragma unroll
      for(int i=0;i<4;i++){
        int row = wm + i*16 + lr, c = ks*4 + lg;
        ah[i] = *(const bf16x8*)(sAhi + swz(row,c)*8);
        if(NPROD==3) al[i] = *(const bf16x8*)(sAlo + swz(row,c)*8);
      }
      #pragma unroll
      for(int j=0;j<2;j++){
        int row = wn + j*16 + lr, c = ks*4 + lg;
        bh[j] = *(const bf16x8*)(sBhi + swz(row,c)*8);
        if(NPROD==3) bl[j] = *(const bf16x8*)(sBlo + swz(row,c)*8);
      }
      #pragma unroll
      for(int i=0;i<4;i++)
        #pragma unroll
        for(int j=0;j<2;j++){
          acc[i][j] = MFMA16(ah[i], bh[j], acc[i][j]);
          if(NPROD==3){
            acc[i][j] = MFMA16(ah[i], bl[j], acc[i][j]);
            acc[i][j] = MFMA16(al[i], bh[j], acc[i][j]);
          }
        }
    }
  }
  #pragma unroll
  for(int i=0;i<4;i++){
    #pragma unroll
    for(int j=0;j<2;j++){
      int row = m0 + wm + i*16 + lg*4;
      int col = n0 + wn + j*16 + lr;
      if(EPI == 1){
        int bb = row >> 11;
        int hh = col >> 6, cc = col & 63;
        short4v pk;
        #pragma unroll
        for(int r=0;r<4;r++) pk[r] = f2bf(acc[i][j][r] * scale);
        long idx = ((long)((bb*8 + hh)*64 + cc) << 11) + (row & 2047);
        *(short4v*)(O0 + idx) = pk;
      } else {
        #pragma unroll
        for(int r=0;r<4;r++){
          float v = acc[i][j][r] * scale;
          long idx = (long)(row + r) * 512 + col;
          if(EPI == 0){
            short hh = f2bf(v);
            O0[idx] = hh;
            O1[idx] = f2bf(v - bf2f(hh));
          } else {
            Of[idx] = v + bias[col];
          }
        }
      }
    }
  }
}

// ---------------- fused attention (r5 skeleton frozen; compute-phase ops cut) ----------------
struct SpreadArgs { float sig2[8]; float nine[8]; float inv2[8]; };

__global__ __launch_bounds__(256) void attn_k(
    const short* __restrict__ qhHi, const short* __restrict__ qhLo,
    const short* __restrict__ khHi, const short* __restrict__ khLo,
    const short* __restrict__ vt,
    const float* __restrict__ coords,
    const unsigned char* __restrict__ kpm,
    short* __restrict__ Xhi, short* __restrict__ Xlo,
    SpreadArgs sa)
{
  __shared__ __attribute__((aligned(16))) short sKhi[64*64];
  __shared__ __attribute__((aligned(16))) short sKlo[64*64];
  __shared__ __attribute__((aligned(16))) short sV[64*64];
  __shared__ float sCj[64][4];
  __shared__ float sM[64];
  __shared__ __attribute__((aligned(16))) short sP[4][16][72]; // per-wave P tile, padded

  const int tid = threadIdx.x, w = tid >> 6, lane = tid & 63;
  const int lr = lane & 15, lg = lane >> 4;
  const int b = blockIdx.z, h = blockIdx.y, i0 = blockIdx.x * 64;
  const float sig2 = sa.sig2[h], nine = sa.nine[h], inv2 = sa.inv2[h];
  // constant RBF factors for the (dominant) d2<=sig2 regime — bit-identical to slow path
  const float argc = sig2 * inv2;
  const float E0 = __expf(-argc), E1 = __expf(argc);
  bf16x8 ones8;
  #pragma unroll
  for(int i=0;i<8;i++) ones8[i] = (short)0x3F80;   // bf16 1.0

  // Q fragments resident in registers (A-frag: row = lane&15, k = (lane>>4)*8)
  long qrow = (long)(b*2048 + i0 + w*16 + lr) * 512 + h*64;
  bf16x8 qhi[2], qlo[2];
  #pragma unroll
  for(int ks=0; ks<2; ks++){
    qhi[ks] = *(const bf16x8*)(qhHi + qrow + ks*32 + lg*8);
    qlo[ks] = *(const bf16x8*)(qhLo + qrow + ks*32 + lg*8);
  }
  // coords of this lane's 4 C-rows + their squared norms
  float ci[4][3], ni[4];
  {
    int r0 = b*2048 + i0 + w*16 + lg*4;
    #pragma unroll
    for(int r=0;r<4;r++){
      ci[r][0] = coords[(long)(r0+r)*3 + 0];
      ci[r][1] = coords[(long)(r0+r)*3 + 1];
      ci[r][2] = coords[(long)(r0+r)*3 + 2];
      ni[r] = ci[r][0]*ci[r][0] + ci[r][1]*ci[r][1] + ci[r][2]*ci[r][2];
    }
  }
  f32x4 oacc[4];
  for(int c=0;c<4;c++) oacc[c] = f32x4{0.f,0.f,0.f,0.f};
  float m[4], l[4];
  for(int r=0;r<4;r++){ m[r] = -1e30f; l[r] = 0.f; }

  for(int jt=0; jt<32; jt++){
    int j0 = jt*64;
    for(int u=tid; u<512; u+=256){
      int row = u>>3, cc = u&7;
      long gk = (long)(b*2048 + j0 + row)*512 + h*64 + cc*8;
      *(bf16x8*)(sKhi + swz(row,cc)*8) = *(const bf16x8*)(khHi + gk);
      *(bf16x8*)(sKlo + swz(row,cc)*8) = *(const bf16x8*)(khLo + gk);
      long gv = ((long)((b*8+h)*64 + row) << 11) + j0 + cc*8;
      *(bf16x8*)(sV + swz(row,cc)*8) = *(const bf16x8*)(vt + gv);
    }
    if(tid < 64){
      long cb = (long)(b*2048 + j0 + tid)*3;
      float cx = coords[cb], cy = coords[cb+1], cz = coords[cb+2];
      sCj[tid][0] = cx; sCj[tid][1] = cy; sCj[tid][2] = cz;
      sCj[tid][3] = cx*cx + cy*cy + cz*cz;
      sM[tid] = kpm[b*2048 + j0 + tid] ? 1.f : 0.f;
    }
    __syncthreads();

    // S = (QK^T)/8, 3-product hi/lo split (scale folded into qh; lo*lo dropped)
    f32x4 s[4];
    #pragma unroll
    for(int jf=0;jf<4;jf++){
      f32x4 t = f32x4{0.f,0.f,0.f,0.f};
      #pragma unroll
      for(int ks=0;ks<2;ks++){
        int row = jf*16 + lr, c = ks*4 + lg;
        bf16x8 bh = *(const bf16x8*)(sKhi + swz(row,c)*8);
        bf16x8 bl = *(const bf16x8*)(sKlo + swz(row,c)*8);
        t = MFMA16(qhi[ks], bh, t);
        t = MFMA16(qhi[ks], bl, t);
        t = MFMA16(qlo[ks], bh, t);
      }
      s[jf] = t;
    }
    // RBF modulation + mask. d2 via dot form; wave-uniform fast path when every
    // element has d2<=sig2 and no key-padding (then tt==sig2 exactly and the
    // factor is the precomputed E0/E1 — bit-identical to the general path).
    float d2a[4][4], kmv[4];
    int ok = 1;
    #pragma unroll
    for(int jf=0;jf<4;jf++){
      int j = jf*16 + lr;
      float cjx = sCj[j][0], cjy = sCj[j][1], cjz = sCj[j][2], nj = sCj[j][3];
      kmv[jf] = sM[j];
      ok &= (kmv[jf] == 0.f);
      #pragma unroll
      for(int r=0;r<4;r++){
        float dot = ci[r][0]*cjx + ci[r][1]*cjy + ci[r][2]*cjz;
        float d2 = fmaf(-2.f, dot, ni[r] + nj);
        d2a[jf][r] = d2;
        ok &= (d2 <= sig2);
      }
    }
    if(__all(ok)){
      #pragma unroll
      for(int jf=0;jf<4;jf++)
        #pragma unroll
        for(int r=0;r<4;r++){
          float sv = s[jf][r];
          s[jf][r] = sv * (sv < 0.f ? E1 : E0);
        }
    } else {
      #pragma unroll
      for(int jf=0;jf<4;jf++){
        float km = kmv[jf];
        #pragma unroll
        for(int r=0;r<4;r++){
          float d2 = d2a[jf][r];
          float tt = fminf(fmaxf(d2, sig2), nine);
          float arg = tt * inv2;
          float sv = s[jf][r];
          sv *= __expf(sv < 0.f ? arg : -arg);
          if(d2 > nine || km != 0.f) sv = -1e30f;
          s[jf][r] = sv;
        }
      }
    }
    // online softmax: row max over the 16-lane column group (unconditional rescale)
    float pm[4];
    #pragma unroll
    for(int r=0;r<4;r++)
      pm[r] = fmaxf(fmaxf(s[0][r], s[1][r]), fmaxf(s[2][r], s[3][r]));
    #pragma unroll
    for(int d=1; d<16; d<<=1){
      #pragma unroll
      for(int r=0;r<4;r++) pm[r] = fmaxf(pm[r], __shfl_xor(pm[r], d));
    }
    float fr[4];
    #pragma unroll
    for(int r=0;r<4;r++){
      float mn = fmaxf(m[r], pm[r]);
      fr[r] = __expf(m[r] - mn);
      m[r] = mn;
      l[r] *= fr[r];
    }
    #pragma unroll
    for(int jf=0;jf<4;jf++)
      #pragma unroll
      for(int r=0;r<4;r++)
        s[jf][r] = __expf(s[jf][r] - m[r]);
    #pragma unroll
    for(int c=0;c<4;c++)
      #pragma unroll
      for(int r=0;r<4;r++) oacc[c][r] *= fr[r];
    // P -> per-wave LDS (C-layout write, A-layout read; same-wave so no barrier)
    #pragma unroll
    for(int jf=0;jf<4;jf++)
      #pragma unroll
      for(int r=0;r<4;r++)
        sP[w][lg*4 + r][jf*16 + lr] = f2bf(s[jf][r]);
    // PV + row-sum of P via a spare MFMA against an all-ones B fragment
    f32x4 psacc = f32x4{0.f,0.f,0.f,0.f};
    #pragma unroll
    for(int js=0;js<2;js++){
      union { bf16x8 v8; short4v h4[2]; } pa;
      pa.h4[0] = *(const short4v*)(&sP[w][lr][js*32 + lg*8]);
      pa.h4[1] = *(const short4v*)(&sP[w][lr][js*32 + lg*8 + 4]);
      #pragma unroll
      for(int cf=0; cf<4; cf++){
        int vrow = cf*16 + lr, vc = js*4 + lg;
        bf16x8 vb = *(const bf16x8*)(sV + swz(vrow,vc)*8);
        oacc[cf] = MFMA16(pa.v8, vb, oacc[cf]);
      }
      psacc = MFMA16(pa.v8, ones8, psacc);
    }
    #pragma unroll
    for(int r=0;r<4;r++) l[r] += psacc[r];
    __syncthreads();
  }
  // epilogue: X[b*2048+i][h*64+c] as hi/lo split for the final GEMM
  #pragma unroll
  for(int cf=0; cf<4; cf++){
    #pragma unroll
    for(int r=0;r<4;r++){
      float v = oacc[cf][r] / l[r];
      long idx = (long)(b*2048 + i0 + w*16 + lg*4 + r)*512 + h*64 + cf*16 + lr;
      short hh = f2bf(v);
      Xhi[idx] = hh;
      Xlo[idx] = f2bf(v - bf2f(hh));
    }
  }
}

// ---------------- host ----------------
extern "C" void kernel_launch(void* const* d_in, const int* in_sizes, int n_in,
                              void* d_out, int out_size, void* d_ws, size_t ws_size,
                              hipStream_t stream){
  const float* q  = (const float*)d_in[0];
  const float* k  = (const float*)d_in[1];
  const float* v  = (const float*)d_in[2];
  const float* coords = (const float*)d_in[3];
  const unsigned char* kpm = (const unsigned char*)d_in[4];
  const float* qp = (const float*)d_in[5];
  const float* kp = (const float*)d_in[6];
  const float* vp = (const float*)d_in[7];
  const float* ow = (const float*)d_in[8];
  const float* ob = (const float*)d_in[9];
  float* out = (float*)d_out;

  char* ws = (char*)d_ws;
  const size_t S = (size_t)4096*512*2;      // one bf16 [4096][512] plane
  const size_t P = (size_t)512*512*2;       // one bf16 [512][512] plane
  if(ws_size < 12*S + 7*P) return;
  short* q_hi = (short*)(ws + 0*S);
  short* q_lo = (short*)(ws + 1*S);
  short* k_hi = (short*)(ws + 2*S);
  short* k_lo = (short*)(ws + 3*S);
  short* v_hi = (short*)(ws + 4*S);
  short* qhHi = (short*)(ws + 5*S);
  short* qhLo = (short*)(ws + 6*S);
  short* khHi = (short*)(ws + 7*S);
  short* khLo = (short*)(ws + 8*S);
  short* vt   = (short*)(ws + 9*S);
  short* Xhi  = (short*)(ws + 10*S);
  short* Xlo  = (short*)(ws + 11*S);
  char* ws2 = ws + 12*S;
  short* BqHi = (short*)(ws2 + 0*P);
  short* BqLo = (short*)(ws2 + 1*P);
  short* BkHi = (short*)(ws2 + 2*P);
  short* BkLo = (short*)(ws2 + 3*P);
  short* BvHi = (short*)(ws2 + 4*P);
  short* WHi  = (short*)(ws2 + 5*P);
  short* WLo  = (short*)(ws2 + 6*P);

  SpreadArgs sa;
  for(int hh=0; hh<8; hh++){
    double t  = (1.0 - 0.02) * (double)hh / 7.0;
    double lg = pow(20.0, t);
    double sp = 3.7 + (lg - 1.0) / 19.0 * (20.0 - 3.7);
    float spf = (float)sp;
    sa.sig2[hh] = spf*spf;
    sa.nine[hh] = 9.f*spf*spf;
    sa.inv2[hh] = 1.f/(2.f*spf*spf);
  }

  const int NQ = 4096*512;
  split3<<<dim3(NQ/256, 3), dim3(256), 0, stream>>>(q, k, v, q_hi, q_lo, k_hi, k_lo, v_hi);
  split_mat<<<dim3(1024), dim3(256), 0, stream>>>(ow, WHi, WLo, 512*512);
  split_proj3<<<dim3(1024, 3), dim3(256), 0, stream>>>(qp, kp, vp, BqHi, BqLo, BkHi, BkLo, BvHi);

  gemm_qkv<<<dim3(32, 8, 3), dim3(256), 0, stream>>>(
      q_hi, q_lo, k_hi, k_lo, v_hi,
      BqHi, BqLo, BkHi, BkLo, BvHi,
      qhHi, qhLo, khHi, khLo, vt);

  attn_k<<<dim3(32, 8, 2), dim3(256), 0, stream>>>(qhHi, qhLo, khHi, khLo, vt,
        coords, kpm, Xhi, Xlo, sa);

  gemm_k<3,2><<<dim3(32, 8), dim3(256), 0, stream>>>(Xhi, Xlo, WHi, WLo,
        nullptr, nullptr, out, ob, 1.f);
}

// Round 8
// 187.766 us; speedup vs baseline: 1.2574x; 1.0516x over previous
//
#include <hip/hip_runtime.h>
#include <hip/hip_bf16.h>
#include <cmath>

typedef __attribute__((ext_vector_type(8))) short bf16x8;
typedef __attribute__((ext_vector_type(4))) float f32x4;
typedef __attribute__((ext_vector_type(4))) short short4v;

#define MFMA16(a,b,c) __builtin_amdgcn_mfma_f32_16x16x32_bf16((a),(b),(c),0,0,0)
#define EXP2F(x) __builtin_amdgcn_exp2f(x)

__device__ __forceinline__ short f2bf(float x){
  unsigned u = __float_as_uint(x);
  u += 0x7fffu + ((u >> 16) & 1u);          // RNE
  return (short)(u >> 16);
}
__device__ __forceinline__ float bf2f(short h){
  return __uint_as_float(((unsigned)(unsigned short)h) << 16);
}
// 16B-chunk XOR swizzle within a [rows][64-short] tile; unit = 8 shorts
__device__ __forceinline__ int swz(int row, int c){ return (row << 3) | (c ^ (row & 7)); }

// ---------------- split kernels ----------------
__global__ void split_mat(const float* __restrict__ src, short* __restrict__ hi,
                          short* __restrict__ lo, int n){
  int i = blockIdx.x * 256 + threadIdx.x;
  if(i >= n) return;
  float x = src[i];
  short h = f2bf(x);
  hi[i] = h;
  if(lo) lo[i] = f2bf(x - bf2f(h));
}

// q,k,v -> hi/lo (v: hi only), one dispatch, float4-vectorized
__global__ void split3(const float* __restrict__ q, const float* __restrict__ k,
                       const float* __restrict__ v,
                       short* __restrict__ q_hi, short* __restrict__ q_lo,
                       short* __restrict__ k_hi, short* __restrict__ k_lo,
                       short* __restrict__ v_hi){
  int y = blockIdx.y;
  int i4 = (blockIdx.x * 256 + threadIdx.x) * 4;
  if(y == 0){
    float4 x = *(const float4*)(q + i4);
    short4v hi, lo;
    float xs[4] = {x.x, x.y, x.z, x.w};
    #pragma unroll
    for(int r=0;r<4;r++){ short h = f2bf(xs[r]); hi[r]=h; lo[r]=f2bf(xs[r]-bf2f(h)); }
    *(short4v*)(q_hi + i4) = hi; *(short4v*)(q_lo + i4) = lo;
  } else if(y == 1){
    float4 x = *(const float4*)(k + i4);
    short4v hi, lo;
    float xs[4] = {x.x, x.y, x.z, x.w};
    #pragma unroll
    for(int r=0;r<4;r++){ short h = f2bf(xs[r]); hi[r]=h; lo[r]=f2bf(xs[r]-bf2f(h)); }
    *(short4v*)(k_hi + i4) = hi; *(short4v*)(k_lo + i4) = lo;
  } else {
    float4 x = *(const float4*)(v + i4);
    short4v hi;
    float xs[4] = {x.x, x.y, x.z, x.w};
    #pragma unroll
    for(int r=0;r<4;r++) hi[r] = f2bf(xs[r]);
    *(short4v*)(v_hi + i4) = hi;
  }
}

// proj [8][512][64] -> BT [512][512], BT[h*64+c][d] = proj[h][d][c]; 3 projections fused
__global__ void split_proj3(const float* __restrict__ qp, const float* __restrict__ kp,
                            const float* __restrict__ vp,
                            short* __restrict__ BqHi, short* __restrict__ BqLo,
                            short* __restrict__ BkHi, short* __restrict__ BkLo,
                            short* __restrict__ BvHi){
  int y = blockIdx.y;
  int i = blockIdx.x * 256 + threadIdx.x;   // i = n*512 + d
  int n = i >> 9, d = i & 511;
  int h = n >> 6, c = n & 63;
  long si = (long)((h << 15) | (d << 6) | c);
  if(y == 0){
    float x = qp[si]; short hh = f2bf(x);
    BqHi[i] = hh; BqLo[i] = f2bf(x - bf2f(hh));
  } else if(y == 1){
    float x = kp[si]; short hh = f2bf(x);
    BkHi[i] = hh; BkLo[i] = f2bf(x - bf2f(hh));
  } else {
    BvHi[i] = f2bf(vp[si]);
  }
}

// ---------------- fused projection GEMM (q,k,v in one dispatch via z) ----------------
// C[4096x512] = A[4096x512] * BT[512x512]^T
// z=0: q (3-prod, hi/lo out, scale 0.125*log2e); z=1: k (3-prod, hi/lo out); z=2: v (1-prod, vt out)
__global__ __launch_bounds__(256) void gemm_qkv(
    const short* __restrict__ q_hi, const short* __restrict__ q_lo,
    const short* __restrict__ k_hi, const short* __restrict__ k_lo,
    const short* __restrict__ v_hi,
    const short* __restrict__ BqHi, const short* __restrict__ BqLo,
    const short* __restrict__ BkHi, const short* __restrict__ BkLo,
    const short* __restrict__ BvHi,
    short* __restrict__ qhHi, short* __restrict__ qhLo,
    short* __restrict__ khHi, short* __restrict__ khLo,
    short* __restrict__ vt)
{
  constexpr int K = 512;
  __shared__ __attribute__((aligned(16))) short sAhi[128*64];
  __shared__ __attribute__((aligned(16))) short sBhi[64*64];
  __shared__ __attribute__((aligned(16))) short sAlo[128*64];
  __shared__ __attribute__((aligned(16))) short sBlo[64*64];
  const int tid = threadIdx.x;
  const int z = blockIdx.z;
  const bool three = (z < 2);
  const short* Ahi = z==0 ? q_hi : z==1 ? k_hi : v_hi;
  const short* Alo = z==0 ? q_lo : k_lo;
  const short* Bhi = z==0 ? BqHi : z==1 ? BkHi : BvHi;
  const short* Blo = z==0 ? BqLo : BkLo;
  const float scale = z==0 ? 0.125f*1.44269504f : 1.f;   // fold log2(e) -> exp2 softmax domain
  const int m0 = blockIdx.x * 128, n0 = blockIdx.y * 64;
  const int w = tid >> 6, lane = tid & 63;
  const int wm = (w >> 1) * 64, wn = (w & 1) * 32;
  const int lr = lane & 15, lg = lane >> 4;

  f32x4 acc[4][2];
  for(int i=0;i<4;i++) for(int j=0;j<2;j++) acc[i][j] = f32x4{0.f,0.f,0.f,0.f};

  for(int kt = 0; kt < K; kt += 64){
    __syncthreads();
    for(int u = tid; u < 1024; u += 256){
      int row = u >> 3, c = u & 7;
      long ga = (long)(m0 + row) * K + kt + c*8;
      *(bf16x8*)(sAhi + swz(row,c)*8) = *(const bf16x8*)(Ahi + ga);
      if(three)
        *(bf16x8*)(sAlo + swz(row,c)*8) = *(const bf16x8*)(Alo + ga);
    }
    for(int u = tid; u < 512; u += 256){
      int row = u >> 3, c = u & 7;
      long ga = (long)(n0 + row) * K + kt + c*8;
      *(bf16x8*)(sBhi + swz(row,c)*8) = *(const bf16x8*)(Bhi + ga);
      if(three)
        *(bf16x8*)(sBlo + swz(row,c)*8) = *(const bf16x8*)(Blo + ga);
    }
    __syncthreads();
    #pragma unroll
    for(int ks = 0; ks < 2; ks++){
      bf16x8 ah[4], al[4], bh[2], bl[2];
      #pragma unroll
      for(int i=0;i<4;i++){
        int row = wm + i*16 + lr, c = ks*4 + lg;
        ah[i] = *(const bf16x8*)(sAhi + swz(row,c)*8);
        if(three) al[i] = *(const bf16x8*)(sAlo + swz(row,c)*8);
      }
      #pragma unroll
      for(int j=0;j<2;j++){
        int row = wn + j*16 + lr, c = ks*4 + lg;
        bh[j] = *(const bf16x8*)(sBhi + swz(row,c)*8);
        if(three) bl[j] = *(const bf16x8*)(sBlo + swz(row,c)*8);
      }
      #pragma unroll
      for(int i=0;i<4;i++)
        #pragma unroll
        for(int j=0;j<2;j++){
          acc[i][j] = MFMA16(ah[i], bh[j], acc[i][j]);
          if(three){
            acc[i][j] = MFMA16(ah[i], bl[j], acc[i][j]);
            acc[i][j] = MFMA16(al[i], bh[j], acc[i][j]);
          }
        }
    }
  }
  // epilogue
  #pragma unroll
  for(int i=0;i<4;i++){
    #pragma unroll
    for(int j=0;j<2;j++){
      int row = m0 + wm + i*16 + lg*4;
      int col = n0 + wn + j*16 + lr;
      if(z == 2){
        int bb = row >> 11;
        int hh = col >> 6, cc = col & 63;
        short4v pk;
        #pragma unroll
        for(int r=0;r<4;r++) pk[r] = f2bf(acc[i][j][r]);
        long idx = ((long)((bb*8 + hh)*64 + cc) << 11) + (row & 2047);
        *(short4v*)(vt + idx) = pk;
      } else {
        short* O0 = z==0 ? qhHi : khHi;
        short* O1 = z==0 ? qhLo : khLo;
        #pragma unroll
        for(int r=0;r<4;r++){
          float v = acc[i][j][r] * scale;
          long idx = (long)(row + r) * 512 + col;
          short hh = f2bf(v);
          O0[idx] = hh;
          O1[idx] = f2bf(v - bf2f(hh));
        }
      }
    }
  }
}

// ---------------- GEMM template (used for the final GEMM) ----------------
template<int NPROD, int EPI>
__global__ __launch_bounds__(256) void gemm_k(
    const short* __restrict__ Ahi, const short* __restrict__ Alo,
    const short* __restrict__ Bhi, const short* __restrict__ Blo,
    short* __restrict__ O0, short* __restrict__ O1,
    float* __restrict__ Of, const float* __restrict__ bias, float scale)
{
  constexpr int K = 512;
  __shared__ __attribute__((aligned(16))) short sAhi[128*64];
  __shared__ __attribute__((aligned(16))) short sBhi[64*64];
  __shared__ __attribute__((aligned(16))) short sAlo[NPROD==3 ? 128*64 : 8];
  __shared__ __attribute__((aligned(16))) short sBlo[NPROD==3 ? 64*64 : 8];
  const int tid = threadIdx.x;
  const int m0 = blockIdx.x * 128, n0 = blockIdx.y * 64;
  const int w = tid >> 6, lane = tid & 63;
  const int wm = (w >> 1) * 64, wn = (w & 1) * 32;
  const int lr = lane & 15, lg = lane >> 4;

  f32x4 acc[4][2];
  for(int i=0;i<4;i++) for(int j=0;j<2;j++) acc[i][j] = f32x4{0.f,0.f,0.f,0.f};

  for(int kt = 0; kt < K; kt += 64){
    __syncthreads();
    for(int u = tid; u < 1024; u += 256){
      int row = u >> 3, c = u & 7;
      long ga = (long)(m0 + row) * K + kt + c*8;
      *(bf16x8*)(sAhi + swz(row,c)*8) = *(const bf16x8*)(Ahi + ga);
      if(NPROD == 3)
        *(bf16x8*)(sAlo + swz(row,c)*8) = *(const bf16x8*)(Alo + ga);
    }
    for(int u = tid; u < 512; u += 256){
      int row = u >> 3, c = u & 7;
      long ga = (long)(n0 + row) * K + kt + c*8;
      *(bf16x8*)(sBhi + swz(row,c)*8) = *(const bf16x8*)(Bhi + ga);
      if(NPROD == 3)
        *(bf16x8*)(sBlo + swz(row,c)*8) = *(const bf16x8*)(Blo + ga);
    }
    __syncthreads();
    #pragma unroll
    for(int ks = 0; ks < 2; ks++){
      bf16x8 ah[4], al[4], bh[2], bl[2];
      #pragma unroll
      for(int i=0;i<4;i++){
        int row = wm + i*16 + lr, c = ks*4 + lg;
        ah[i] = *(const bf16x8*)(sAhi + swz(row,c)*8);
        if(NPROD==3) al[i] = *(const bf16x8*)(sAlo + swz(row,c)*8);
      }
      #pragma unroll
      for(int j=0;j<2;j++){
        int row = wn + j*16 + lr, c = ks*4 + lg;
        bh[j] = *(const bf16x8*)(sBhi + swz(row,c)*8);
        if(NPROD==3) bl[j] = *(const bf16x8*)(sBlo + swz(row,c)*8);
      }
      #pragma unroll
      for(int i=0;i<4;i++)
        #pragma unroll
        for(int j=0;j<2;j++){
          acc[i][j] = MFMA16(ah[i], bh[j], acc[i][j]);
          if(NPROD==3){
            acc[i][j] = MFMA16(ah[i], bl[j], acc[i][j]);
            acc[i][j] = MFMA16(al[i], bh[j], acc[i][j]);
          }
        }
    }
  }
  #pragma unroll
  for(int i=0;i<4;i++){
    #pragma unroll
    for(int j=0;j<2;j++){
      int row = m0 + wm + i*16 + lg*4;
      int col = n0 + wn + j*16 + lr;
      if(EPI == 1){
        int bb = row >> 11;
        int hh = col >> 6, cc = col & 63;
        short4v pk;
        #pragma unroll
        for(int r=0;r<4;r++) pk[r] = f2bf(acc[i][j][r] * scale);
        long idx = ((long)((bb*8 + hh)*64 + cc) << 11) + (row & 2047);
        *(short4v*)(O0 + idx) = pk;
      } else {
        #pragma unroll
        for(int r=0;r<4;r++){
          float v = acc[i][j][r] * scale;
          long idx = (long)(row + r) * 512 + col;
          if(EPI == 0){
            short hh = f2bf(v);
            O0[idx] = hh;
            O1[idx] = f2bf(v - bf2f(hh));
          } else {
            Of[idx] = v + bias[col];
          }
        }
      }
    }
  }
}

// ---------------- fused attention (r5 skeleton frozen; XCD swizzle + exp2 domain) ----------------
struct SpreadArgs { float sig2[8]; float nine[8]; float inv2[8]; };

__global__ __launch_bounds__(256) void attn_k(
    const short* __restrict__ qhHi, const short* __restrict__ qhLo,
    const short* __restrict__ khHi, const short* __restrict__ khLo,
    const short* __restrict__ vt,
    const float* __restrict__ coords,
    const unsigned char* __restrict__ kpm,
    short* __restrict__ Xhi, short* __restrict__ Xlo,
    SpreadArgs sa)
{
  __shared__ __attribute__((aligned(16))) short sKhi[64*64];
  __shared__ __attribute__((aligned(16))) short sKlo[64*64];
  __shared__ __attribute__((aligned(16))) short sV[64*64];
  __shared__ float sCj[64][4];
  __shared__ float sM[64];
  __shared__ __attribute__((aligned(16))) short sP[4][16][72]; // per-wave P tile, padded

  const int tid = threadIdx.x, w = tid >> 6, lane = tid & 63;
  const int lr = lane & 15, lg = lane >> 4;
  // XCD-locality swizzle (index-only): each XCD owns 2 (b,h) pairs, 32 i-blocks each.
  // Dispatch round-robins linear id across 8 XCDs -> xcd = L&7 keeps a pair's
  // 32 i-blocks (and their shared 786KB K/V) on one XCD's L2.
  const int L = blockIdx.x;
  const int xcd = L & 7, ix = L >> 3;          // ix in [0,64)
  const int pair = xcd*2 + (ix >> 5);          // [0,16)
  const int b = pair >> 3, h = pair & 7, i0 = (ix & 31) * 64;
  const float sig2 = sa.sig2[h], nine = sa.nine[h], inv2 = sa.inv2[h];
  // constant RBF factors for the (dominant) d2<=sig2 regime — bit-identical to slow path
  const float argc = sig2 * inv2;
  const float E0 = __expf(-argc), E1 = __expf(argc);
  bf16x8 ones8;
  #pragma unroll
  for(int i=0;i<8;i++) ones8[i] = (short)0x3F80;   // bf16 1.0

  // Q fragments resident in registers (A-frag: row = lane&15, k = (lane>>4)*8)
  long qrow = (long)(b*2048 + i0 + w*16 + lr) * 512 + h*64;
  bf16x8 qhi[2], qlo[2];
  #pragma unroll
  for(int ks=0; ks<2; ks++){
    qhi[ks] = *(const bf16x8*)(qhHi + qrow + ks*32 + lg*8);
    qlo[ks] = *(const bf16x8*)(qhLo + qrow + ks*32 + lg*8);
  }
  // coords of this lane's 4 C-rows + their squared norms
  float ci[4][3], ni[4];
  {
    int r0 = b*2048 + i0 + w*16 + lg*4;
    #pragma unroll
    for(int r=0;r<4;r++){
      ci[r][0] = coords[(long)(r0+r)*3 + 0];
      ci[r][1] = coords[(long)(r0+r)*3 + 1];
      ci[r][2] = coords[(long)(r0+r)*3 + 2];
      ni[r] = ci[r][0]*ci[r][0] + ci[r][1]*ci[r][1] + ci[r][2]*ci[r][2];
    }
  }
  f32x4 oacc[4];
  for(int c=0;c<4;c++) oacc[c] = f32x4{0.f,0.f,0.f,0.f};
  float m[4], l[4];
  for(int r=0;r<4;r++){ m[r] = -1e30f; l[r] = 0.f; }

  for(int jt=0; jt<32; jt++){
    int j0 = jt*64;
    for(int u=tid; u<512; u+=256){
      int row = u>>3, cc = u&7;
      long gk = (long)(b*2048 + j0 + row)*512 + h*64 + cc*8;
      *(bf16x8*)(sKhi + swz(row,cc)*8) = *(const bf16x8*)(khHi + gk);
      *(bf16x8*)(sKlo + swz(row,cc)*8) = *(const bf16x8*)(khLo + gk);
      long gv = ((long)((b*8+h)*64 + row) << 11) + j0 + cc*8;
      *(bf16x8*)(sV + swz(row,cc)*8) = *(const bf16x8*)(vt + gv);
    }
    if(tid < 64){
      long cb = (long)(b*2048 + j0 + tid)*3;
      float cx = coords[cb], cy = coords[cb+1], cz = coords[cb+2];
      sCj[tid][0] = cx; sCj[tid][1] = cy; sCj[tid][2] = cz;
      sCj[tid][3] = cx*cx + cy*cy + cz*cz;
      sM[tid] = kpm[b*2048 + j0 + tid] ? 1.f : 0.f;
    }
    __syncthreads();

    // S2 = (QK^T)/8*log2e, 3-product hi/lo split (scales folded into qh)
    f32x4 s[4];
    #pragma unroll
    for(int jf=0;jf<4;jf++){
      f32x4 t = f32x4{0.f,0.f,0.f,0.f};
      #pragma unroll
      for(int ks=0;ks<2;ks++){
        int row = jf*16 + lr, c = ks*4 + lg;
        bf16x8 bh = *(const bf16x8*)(sKhi + swz(row,c)*8);
        bf16x8 bl = *(const bf16x8*)(sKlo + swz(row,c)*8);
        t = MFMA16(qhi[ks], bh, t);
        t = MFMA16(qhi[ks], bl, t);
        t = MFMA16(qlo[ks], bh, t);
      }
      s[jf] = t;
    }
    // RBF modulation + mask (multiplicative factor commutes with log2e scaling)
    float d2a[4][4], kmv[4];
    int ok = 1;
    #pragma unroll
    for(int jf=0;jf<4;jf++){
      int j = jf*16 + lr;
      float cjx = sCj[j][0], cjy = sCj[j][1], cjz = sCj[j][2], nj = sCj[j][3];
      kmv[jf] = sM[j];
      ok &= (kmv[jf] == 0.f);
      #pragma unroll
      for(int r=0;r<4;r++){
        float dot = ci[r][0]*cjx + ci[r][1]*cjy + ci[r][2]*cjz;
        float d2 = fmaf(-2.f, dot, ni[r] + nj);
        d2a[jf][r] = d2;
        ok &= (d2 <= sig2);
      }
    }
    if(__all(ok)){
      #pragma unroll
      for(int jf=0;jf<4;jf++)
        #pragma unroll
        for(int r=0;r<4;r++){
          float sv = s[jf][r];
          s[jf][r] = sv * (sv < 0.f ? E1 : E0);
        }
    } else {
      #pragma unroll
      for(int jf=0;jf<4;jf++){
        float km = kmv[jf];
        #pragma unroll
        for(int r=0;r<4;r++){
          float d2 = d2a[jf][r];
          float tt = fminf(fmaxf(d2, sig2), nine);
          float arg = tt * inv2;
          float sv = s[jf][r];
          sv *= __expf(sv < 0.f ? arg : -arg);
          if(d2 > nine || km != 0.f) sv = -1e30f;
          s[jf][r] = sv;
        }
      }
    }
    // online softmax in exp2 domain (logits pre-scaled by log2e)
    float pm[4];
    #pragma unroll
    for(int r=0;r<4;r++)
      pm[r] = fmaxf(fmaxf(s[0][r], s[1][r]), fmaxf(s[2][r], s[3][r]));
    #pragma unroll
    for(int d=1; d<16; d<<=1){
      #pragma unroll
      for(int r=0;r<4;r++) pm[r] = fmaxf(pm[r], __shfl_xor(pm[r], d));
    }
    float fr[4];
    #pragma unroll
    for(int r=0;r<4;r++){
      float mn = fmaxf(m[r], pm[r]);
      fr[r] = EXP2F(m[r] - mn);
      m[r] = mn;
      l[r] *= fr[r];
    }
    #pragma unroll
    for(int jf=0;jf<4;jf++)
      #pragma unroll
      for(int r=0;r<4;r++)
        s[jf][r] = EXP2F(s[jf][r] - m[r]);
    #pragma unroll
    for(int c=0;c<4;c++)
      #pragma unroll
      for(int r=0;r<4;r++) oacc[c][r] *= fr[r];
    // P -> per-wave LDS (C-layout write, A-layout read; same-wave so no barrier)
    #pragma unroll
    for(int jf=0;jf<4;jf++)
      #pragma unroll
      for(int r=0;r<4;r++)
        sP[w][lg*4 + r][jf*16 + lr] = f2bf(s[jf][r]);
    // PV + row-sum of P via a spare MFMA against an all-ones B fragment
    f32x4 psacc = f32x4{0.f,0.f,0.f,0.f};
    #pragma unroll
    for(int js=0;js<2;js++){
      union { bf16x8 v8; short4v h4[2]; } pa;
      pa.h4[0] = *(const short4v*)(&sP[w][lr][js*32 + lg*8]);
      pa.h4[1] = *(const short4v*)(&sP[w][lr][js*32 + lg*8 + 4]);
      #pragma unroll
      for(int cf=0; cf<4; cf++){
        int vrow = cf*16 + lr, vc = js*4 + lg;
        bf16x8 vb = *(const bf16x8*)(sV + swz(vrow,vc)*8);
        oacc[cf] = MFMA16(pa.v8, vb, oacc[cf]);
      }
      psacc = MFMA16(pa.v8, ones8, psacc);
    }
    #pragma unroll
    for(int r=0;r<4;r++) l[r] += psacc[r];
    __syncthreads();
  }
  // epilogue: X[b*2048+i][h*64+c] as hi/lo split for the final GEMM
  #pragma unroll
  for(int cf=0; cf<4; cf++){
    #pragma unroll
    for(int r=0;r<4;r++){
      float v = oacc[cf][r] / l[r];
      long idx = (long)(b*2048 + i0 + w*16 + lg*4 + r)*512 + h*64 + cf*16 + lr;
      short hh = f2bf(v);
      Xhi[idx] = hh;
      Xlo[idx] = f2bf(v - bf2f(hh));
    }
  }
}

// ---------------- host ----------------
extern "C" void kernel_launch(void* const* d_in, const int* in_sizes, int n_in,
                              void* d_out, int out_size, void* d_ws, size_t ws_size,
                              hipStream_t stream){
  const float* q  = (const float*)d_in[0];
  const float* k  = (const float*)d_in[1];
  const float* v  = (const float*)d_in[2];
  const float* coords = (const float*)d_in[3];
  const unsigned char* kpm = (const unsigned char*)d_in[4];
  const float* qp = (const float*)d_in[5];
  const float* kp = (const float*)d_in[6];
  const float* vp = (const float*)d_in[7];
  const float* ow = (const float*)d_in[8];
  const float* ob = (const float*)d_in[9];
  float* out = (float*)d_out;

  char* ws = (char*)d_ws;
  const size_t S = (size_t)4096*512*2;      // one bf16 [4096][512] plane
  const size_t P = (size_t)512*512*2;       // one bf16 [512][512] plane
  if(ws_size < 12*S + 7*P) return;
  short* q_hi = (short*)(ws + 0*S);
  short* q_lo = (short*)(ws + 1*S);
  short* k_hi = (short*)(ws + 2*S);
  short* k_lo = (short*)(ws + 3*S);
  short* v_hi = (short*)(ws + 4*S);
  short* qhHi = (short*)(ws + 5*S);
  short* qhLo = (short*)(ws + 6*S);
  short* khHi = (short*)(ws + 7*S);
  short* khLo = (short*)(ws + 8*S);
  short* vt   = (short*)(ws + 9*S);
  short* Xhi  = (short*)(ws + 10*S);
  short* Xlo  = (short*)(ws + 11*S);
  char* ws2 = ws + 12*S;
  short* BqHi = (short*)(ws2 + 0*P);
  short* BqLo = (short*)(ws2 + 1*P);
  short* BkHi = (short*)(ws2 + 2*P);
  short* BkLo = (short*)(ws2 + 3*P);
  short* BvHi = (short*)(ws2 + 4*P);
  short* WHi  = (short*)(ws2 + 5*P);
  short* WLo  = (short*)(ws2 + 6*P);

  SpreadArgs sa;
  for(int hh=0; hh<8; hh++){
    double t  = (1.0 - 0.02) * (double)hh / 7.0;
    double lg = pow(20.0, t);
    double sp = 3.7 + (lg - 1.0) / 19.0 * (20.0 - 3.7);
    float spf = (float)sp;
    sa.sig2[hh] = spf*spf;
    sa.nine[hh] = 9.f*spf*spf;
    sa.inv2[hh] = 1.f/(2.f*spf*spf);
  }

  const int NQ = 4096*512;
  split3<<<dim3(NQ/1024, 3), dim3(256), 0, stream>>>(q, k, v, q_hi, q_lo, k_hi, k_lo, v_hi);
  split_mat<<<dim3(1024), dim3(256), 0, stream>>>(ow, WHi, WLo, 512*512);
  split_proj3<<<dim3(1024, 3), dim3(256), 0, stream>>>(qp, kp, vp, BqHi, BqLo, BkHi, BkLo, BvHi);

  gemm_qkv<<<dim3(32, 8, 3), dim3(256), 0, stream>>>(
      q_hi, q_lo, k_hi, k_lo, v_hi,
      BqHi, BqLo, BkHi, BkLo, BvHi,
      qhHi, qhLo, khHi, khLo, vt);

  attn_k<<<dim3(512), dim3(256), 0, stream>>>(qhHi, qhLo, khHi, khLo, vt,
        coords, kpm, Xhi, Xlo, sa);

  gemm_k<3,2><<<dim3(32, 8), dim3(256), 0, stream>>>(Xhi, Xlo, WHi, WLo,
        nullptr, nullptr, out, ob, 1.f);
}